// Round 5
// baseline (56.125 us; speedup 1.0000x reference)
//
#include <hip/hip_runtime.h>
#include <hip/hip_bf16.h>

// Problem constants (fixed by setup_inputs): B=32768, D=768, C=200.
#define NROWS 32768
#define DIMS  768
#define NC    200
#define CPAD  256            // centers padded to 256 zero rows
#define KSTEP 32
#define NSTEP (DIMS / KSTEP) // 24
#define ROWSB 32             // rows per block
#define LDA   776            // 768+8 pad shorts; stride 1552 B = 97 x 16B (odd) -> 2-way LDS conflicts (free)

typedef __attribute__((ext_vector_type(8))) short short8;   // 8 bf16
typedef __attribute__((ext_vector_type(4))) short short4v;  // 4 bf16 = 8 B
typedef __attribute__((ext_vector_type(4))) float f32x4;

__device__ __forceinline__ short f2bfs(float f) {
  union { float f; unsigned u; } x; x.f = f;
  unsigned u = x.u;
  unsigned r = u + 0x7fffu + ((u >> 16) & 1u);
  return (short)(r >> 16);
}

// Kernel 1: L2-normalize centers -> bf16, K-step-blocked layout:
// (c,d) -> cnb2[(d>>5)*CPAD*KSTEP + c*KSTEP + (d&31)]
// Each (16-col x 32-k) B-fragment is a contiguous 1 KB run -> coalesced wave loads.
// Also zeroes the output scalar (replaces a separate memset dispatch).
__global__ __launch_bounds__(256) void prep_centers_k(const float* __restrict__ centers,
                                                      short* __restrict__ cnb2,
                                                      float* __restrict__ out) {
  const int c = blockIdx.x;
  const int tid = threadIdx.x;
  if (c == 0 && tid == 0) out[0] = 0.f;
  if (c >= NC) {
    for (int d = tid; d < DIMS; d += 256)
      cnb2[(d >> 5) * (CPAD * KSTEP) + c * KSTEP + (d & 31)] = 0;
    return;
  }
  float ssq = 0.f;
  for (int d = tid; d < DIMS; d += 256) {
    float v = centers[c * DIMS + d];
    ssq += v * v;
  }
#pragma unroll
  for (int off = 32; off > 0; off >>= 1) ssq += __shfl_down(ssq, off);
  __shared__ float red[4];
  const int wid = tid >> 6, lane = tid & 63;
  if (lane == 0) red[wid] = ssq;
  __syncthreads();
  const float tot = red[0] + red[1] + red[2] + red[3];
  const float inv = 1.f / fmaxf(sqrtf(tot), 1e-8f);
  for (int d = tid; d < DIMS; d += 256)
    cnb2[(d >> 5) * (CPAD * KSTEP) + c * KSTEP + (d & 31)] =
        f2bfs(centers[c * DIMS + d] * inv);
}

// Kernel 2: block = 4 waves = 32 rows x 256 cols. A tile staged to LDS ONCE
// (one barrier); K-loop is barrier-free: 2 ds_read_b128 + 4 coalesced L2 B-loads
// + 8 MFMA per step. B comes straight from L2 (cnb2 = 384 KB, L2-resident).
// MFMA frag mapping (verified rounds 2-4): A lane=A[m][k], m=lane&15, k=kg*8+j;
// B lane=B[k][n], n=lane&15, k=kg*8+j; D: col=lane&15, row=kg*4+reg.
__global__ __launch_bounds__(256) void cos_loss_k(
    const float* __restrict__ feats,
    const short* __restrict__ cnb2,
    const int* __restrict__ labels,
    const int* __restrict__ labelled,
    float* __restrict__ out) {
  const int tid = threadIdx.x;
  const int w = tid >> 6;      // wave id = column group (64 cols)
  const int lane = tid & 63;
  const int m = lane & 15;
  const int kg = lane >> 4;
  const int rowBase = blockIdx.x * ROWSB;

  __shared__ short As[ROWSB][LDA];      // 49664 B
  __shared__ float invs[ROWSB];
  __shared__ int   labLds[ROWSB];
  __shared__ int   lblLds[ROWSB];
  __shared__ float l1part[4][ROWSB];
  __shared__ float alpart[4][ROWSB];

  if (tid < ROWSB) {
    labLds[tid] = labels[rowBase + tid];
    lblLds[tid] = labelled[rowBase + tid];
  }

  // ---- Stage A once: thread -> row tid>>3 (8 thr/row), 24 float4 chunks ----
  {
    const int r = tid >> 3;          // 0..31
    const int c = tid & 7;           // 0..7
    const float* src = feats + (size_t)(rowBase + r) * DIMS;
    float ssq = 0.f;
#pragma unroll
    for (int j = 0; j < 24; ++j) {
      const int col = (c + j * 8) * 4;           // float index; 8 lanes cover 128 B
      const float4 v = *(const float4*)(src + col);
      ssq += v.x * v.x + v.y * v.y + v.z * v.z + v.w * v.w;
      short4v s4;
      s4[0] = f2bfs(v.x); s4[1] = f2bfs(v.y); s4[2] = f2bfs(v.z); s4[3] = f2bfs(v.w);
      *(short4v*)(&As[r][col]) = s4;
    }
#pragma unroll
    for (int off = 1; off < 8; off <<= 1) ssq += __shfl_xor(ssq, off);
    if (c == 0) invs[r] = 1.f / fmaxf(sqrtf(ssq), 1e-8f);
  }
  __syncthreads();

  // ---- Barrier-free K-loop ----
  f32x4 acc[2][4];
#pragma unroll
  for (int mi = 0; mi < 2; ++mi)
#pragma unroll
    for (int ni = 0; ni < 4; ++ni) acc[mi][ni] = (f32x4){0.f, 0.f, 0.f, 0.f};

  const short* a0p = &As[m][kg * 8];
  const short* a1p = &As[16 + m][kg * 8];
  // B frag base: col = w*64 + m, within-step offset col*32 + kg*8
  const short* bp = cnb2 + (size_t)(w * 64 + m) * KSTEP + kg * 8;

#pragma unroll 4
  for (int ks = 0; ks < NSTEP; ++ks) {
    const short8 a0 = *(const short8*)(a0p + ks * KSTEP);
    const short8 a1 = *(const short8*)(a1p + ks * KSTEP);
    const short* bs = bp + (size_t)ks * (CPAD * KSTEP);
#pragma unroll
    for (int ni = 0; ni < 4; ++ni) {
      const short8 bf = *(const short8*)(bs + ni * (16 * KSTEP));
      acc[0][ni] = __builtin_amdgcn_mfma_f32_16x16x32_bf16(a0, bf, acc[0][ni], 0, 0, 0);
      acc[1][ni] = __builtin_amdgcn_mfma_f32_16x16x32_bf16(a1, bf, acc[1][ni], 0, 0, 0);
    }
  }

  // ---- Epilogue: per-row l1 and label-|cos| ----
#pragma unroll
  for (int mi = 0; mi < 2; ++mi) {
    float l1r[4] = {0.f, 0.f, 0.f, 0.f};
    float alr[4] = {0.f, 0.f, 0.f, 0.f};
    float iv[4];
    int labr[4];
#pragma unroll
    for (int r = 0; r < 4; ++r) {
      const int row = mi * 16 + kg * 4 + r;
      iv[r] = invs[row];
      labr[r] = labLds[row];
    }
#pragma unroll
    for (int ni = 0; ni < 4; ++ni) {
      const int col = w * 64 + ni * 16 + m;
#pragma unroll
      for (int r = 0; r < 4; ++r) {
        const float a = fabsf(acc[mi][ni][r] * iv[r]);
        l1r[r] += a;
        if (col == labr[r]) alr[r] += a;
      }
    }
#pragma unroll
    for (int r = 0; r < 4; ++r) {
#pragma unroll
      for (int off = 1; off < 16; off <<= 1) {
        l1r[r] += __shfl_xor(l1r[r], off);
        alr[r] += __shfl_xor(alr[r], off);
      }
    }
    if (m == 0) {
#pragma unroll
      for (int r = 0; r < 4; ++r) {
        l1part[w][mi * 16 + kg * 4 + r] = l1r[r];
        alpart[w][mi * 16 + kg * 4 + r] = alr[r];
      }
    }
  }
  __syncthreads();

  if (tid < ROWSB) {
    const float L = l1part[0][tid] + l1part[1][tid] + l1part[2][tid] + l1part[3][tid];
    const float A = alpart[0][tid] + alpart[1][tid] + alpart[2][tid] + alpart[3][tid];
    float c = lblLds[tid] ? (L - 2.f * A) / fmaxf(L, 1e-12f) : 0.f;
#pragma unroll
    for (int off = 1; off < 32; off <<= 1) c += __shfl_xor(c, off);
    if (tid == 0) atomicAdd(out, c);
  }
}

extern "C" void kernel_launch(void* const* d_in, const int* in_sizes, int n_in,
                              void* d_out, int out_size, void* d_ws, size_t ws_size,
                              hipStream_t stream) {
  const float* feats = (const float*)d_in[0];
  const float* centers = (const float*)d_in[1];
  const int* labels = (const int*)d_in[2];
  const int* labelled = (const int*)d_in[3];
  float* out = (float*)d_out;
  short* cnb2 = (short*)d_ws;  // [24][256][32] bf16 = 393216 B

  prep_centers_k<<<CPAD, 256, 0, stream>>>(centers, cnb2, out);
  cos_loss_k<<<NROWS / ROWSB, 256, 0, stream>>>(feats, cnb2, labels, labelled, out);
}

// Round 6
// 38.013 us; speedup vs baseline: 1.4765x; 1.4765x over previous
//
#include <hip/hip_runtime.h>
#include <hip/hip_bf16.h>

// Problem constants: B=32768, D=768, C=200.
#define NROWS 32768
#define DIMS  768
#define NC    200
#define CPAD  256
#define KSTEP 32
#define NSTEP (DIMS / KSTEP)   // 24
#define ROWSB 64               // M-tile rows per block

typedef __attribute__((ext_vector_type(8))) short short8;   // 8 bf16
typedef __attribute__((ext_vector_type(4))) float f32x4;

__device__ __forceinline__ unsigned pk_bf16(float lo, float hi) {
  // v_cvt_pk_bf16_f32 via compiler (RNE) — guide T12: don't hand-write
  union { __hip_bfloat162 h; unsigned u; } c;
  c.h = __float22bfloat162_rn(make_float2(lo, hi));
  return c.u;
}

// Kernel 1: L2-normalize centers -> bf16, K-blocked layout:
// (c,d) -> cnb2[(d>>5)*CPAD*KSTEP + c*KSTEP + (d&31)]; rows >= NC zero.
// Also zeroes the output scalar.
__global__ __launch_bounds__(256) void prep_centers_k(const float* __restrict__ centers,
                                                      short* __restrict__ cnb2,
                                                      float* __restrict__ out) {
  const int c = blockIdx.x;
  const int tid = threadIdx.x;
  if (c == 0 && tid == 0) out[0] = 0.f;
  if (c >= NC) {
    for (int d = tid; d < DIMS; d += 256)
      cnb2[(d >> 5) * (CPAD * KSTEP) + c * KSTEP + (d & 31)] = 0;
    return;
  }
  float ssq = 0.f;
  for (int d = tid; d < DIMS; d += 256) {
    float v = centers[c * DIMS + d];
    ssq += v * v;
  }
#pragma unroll
  for (int off = 32; off > 0; off >>= 1) ssq += __shfl_down(ssq, off);
  __shared__ float red[4];
  const int wid = tid >> 6, lane = tid & 63;
  if (lane == 0) red[wid] = ssq;
  __syncthreads();
  const float tot = red[0] + red[1] + red[2] + red[3];
  const float inv = 1.f / fmaxf(sqrtf(tot), 1e-8f);
  for (int d = tid; d < DIMS; d += 256) {
    const float v = centers[c * DIMS + d] * inv;
    union { __hip_bfloat16 h; short s; } cv;
    cv.h = __float2bfloat16(v);
    cnb2[(d >> 5) * (CPAD * KSTEP) + c * KSTEP + (d & 31)] = cv.s;
  }
}

// Kernel 2: dbuf LDS-tiled GEMM. Block = 4 waves = 64 rows x 256 cols, BK=32.
// Wave w owns cols w*64.. (wave tile 64x64, acc[4][4]).
// LDS tiles: 64-B rows (32 shorts), quad index XOR-swizzled by ((idx>>1)&3)
// on BOTH write and read (involution) -> 2-way conflicts only (free).
// MFMA frag mapping (verified rounds 2-5): A lane=A[row][k], row sel m=lane&15,
// k=kg*8+j (kg=lane>>4); B lane=B[k][col], col sel m; D: col=m, row=kg*4+reg.
__global__ __launch_bounds__(256) void cos_loss_k(
    const float* __restrict__ feats,
    const short* __restrict__ cnb2,
    const int* __restrict__ labels,
    const int* __restrict__ labelled,
    float* __restrict__ out) {
  const int tid = threadIdx.x;
  const int w = tid >> 6;            // wave id = column group (64 cols)
  const int lane = tid & 63;
  const int m = lane & 15;
  const int kg = lane >> 4;
  const int swzf = (m >> 1) & 3;     // frag-read swizzle (same for A and B rows/cols)
  const int rowBase = blockIdx.x * ROWSB;

  __shared__ short As[2][ROWSB][32];   // 8 KB
  __shared__ short Bs[2][CPAD][32];    // 32 KB
  __shared__ float invs[ROWSB];
  __shared__ int   labLds[ROWSB];
  __shared__ int   lblLds[ROWSB];
  __shared__ float l1part[4][ROWSB];
  __shared__ float alpart[4][ROWSB];

  if (tid < ROWSB) {
    labLds[tid] = labels[rowBase + tid];
    lblLds[tid] = labelled[rowBase + tid];
  }

  // ---- staging assignments ----
  // A: thread -> row tid>>2, quad akg=tid&3 (8 floats -> 8 bf16 = one b128 quad)
  const int arow = tid >> 2;
  const int akg  = tid & 3;
  const int aswz = (arow >> 1) & 3;
  const float* asrc = feats + (size_t)(rowBase + arow) * DIMS + akg * 8;
  short* adst0 = &As[0][arow][(akg ^ aswz) * 8];
  short* adst1 = &As[1][arow][(akg ^ aswz) * 8];
  // B: thread -> col tid, copies all 32 k (64 B contiguous in cnb2) as 4 quads
  const int bcol = tid;
  const int bswz = (bcol >> 1) & 3;
  const short* bsrc = cnb2 + bcol * KSTEP;

  f32x4 acc[4][4];
#pragma unroll
  for (int mi = 0; mi < 4; ++mi)
#pragma unroll
    for (int ni = 0; ni < 4; ++ni) acc[mi][ni] = (f32x4){0.f, 0.f, 0.f, 0.f};

  float ssq = 0.f;

  // ---- prologue: stage step 0 into buffer 0 ----
  {
    const float4 va = *(const float4*)(asrc);
    const float4 vb = *(const float4*)(asrc + 4);
    ssq += va.x*va.x + va.y*va.y + va.z*va.z + va.w*va.w;
    ssq += vb.x*vb.x + vb.y*vb.y + vb.z*vb.z + vb.w*vb.w;
    union { short8 s; unsigned u[4]; } p;
    p.u[0] = pk_bf16(va.x, va.y); p.u[1] = pk_bf16(va.z, va.w);
    p.u[2] = pk_bf16(vb.x, vb.y); p.u[3] = pk_bf16(vb.z, vb.w);
    *(short8*)adst0 = p.s;
    const short8 b0 = *(const short8*)(bsrc + 0);
    const short8 b1 = *(const short8*)(bsrc + 8);
    const short8 b2 = *(const short8*)(bsrc + 16);
    const short8 b3 = *(const short8*)(bsrc + 24);
    *(short8*)(&Bs[0][bcol][((0 ^ bswz)) * 8]) = b0;
    *(short8*)(&Bs[0][bcol][((1 ^ bswz)) * 8]) = b1;
    *(short8*)(&Bs[0][bcol][((2 ^ bswz)) * 8]) = b2;
    *(short8*)(&Bs[0][bcol][((3 ^ bswz)) * 8]) = b3;
  }
  __syncthreads();

  // ---- main loop: prefetch(s+1) -> compute(s) -> cvt+ds_write(s+1) -> barrier ----
#pragma unroll 2
  for (int ks = 0; ks < NSTEP; ++ks) {
    const int cur = ks & 1, nxt = cur ^ 1;
    float4 va, vb;
    short8 b0, b1, b2, b3;
    if (ks < NSTEP - 1) {
      const float* ap = asrc + (ks + 1) * KSTEP;
      va = *(const float4*)(ap);
      vb = *(const float4*)(ap + 4);
      const short* bp = bsrc + (size_t)(ks + 1) * (CPAD * KSTEP);
      b0 = *(const short8*)(bp + 0);
      b1 = *(const short8*)(bp + 8);
      b2 = *(const short8*)(bp + 16);
      b3 = *(const short8*)(bp + 24);
    }
    // compute on cur
    {
      short8 af[4], bf[4];
#pragma unroll
      for (int mi = 0; mi < 4; ++mi)
        af[mi] = *(const short8*)(&As[cur][mi * 16 + m][((kg ^ swzf)) * 8]);
#pragma unroll
      for (int ni = 0; ni < 4; ++ni)
        bf[ni] = *(const short8*)(&Bs[cur][w * 64 + ni * 16 + m][((kg ^ swzf)) * 8]);
#pragma unroll
      for (int mi = 0; mi < 4; ++mi)
#pragma unroll
        for (int ni = 0; ni < 4; ++ni)
          acc[mi][ni] = __builtin_amdgcn_mfma_f32_16x16x32_bf16(af[mi], bf[ni], acc[mi][ni], 0, 0, 0);
    }
    if (ks < NSTEP - 1) {
      ssq += va.x*va.x + va.y*va.y + va.z*va.z + va.w*va.w;
      ssq += vb.x*vb.x + vb.y*vb.y + vb.z*vb.z + vb.w*vb.w;
      union { short8 s; unsigned u[4]; } p;
      p.u[0] = pk_bf16(va.x, va.y); p.u[1] = pk_bf16(va.z, va.w);
      p.u[2] = pk_bf16(vb.x, vb.y); p.u[3] = pk_bf16(vb.z, vb.w);
      *(short8*)(nxt ? adst1 : adst0) = p.s;
      *(short8*)(&Bs[nxt][bcol][((0 ^ bswz)) * 8]) = b0;
      *(short8*)(&Bs[nxt][bcol][((1 ^ bswz)) * 8]) = b1;
      *(short8*)(&Bs[nxt][bcol][((2 ^ bswz)) * 8]) = b2;
      *(short8*)(&Bs[nxt][bcol][((3 ^ bswz)) * 8]) = b3;
    }
    __syncthreads();
  }

  // ---- row inverse norms (fp32) ----
  ssq += __shfl_xor(ssq, 1);
  ssq += __shfl_xor(ssq, 2);
  if ((tid & 3) == 0) invs[arow] = 1.f / fmaxf(sqrtf(ssq), 1e-8f);
  __syncthreads();

  // ---- epilogue: per-row l1 and label-|cos| ----
#pragma unroll
  for (int mi = 0; mi < 4; ++mi) {
    float l1r[4] = {0.f, 0.f, 0.f, 0.f};
    float alr[4] = {0.f, 0.f, 0.f, 0.f};
    float iv[4];
    int labr[4];
#pragma unroll
    for (int r = 0; r < 4; ++r) {
      const int row = mi * 16 + kg * 4 + r;
      iv[r] = invs[row];
      labr[r] = labLds[row];
    }
#pragma unroll
    for (int ni = 0; ni < 4; ++ni) {
      const int col = w * 64 + ni * 16 + m;
#pragma unroll
      for (int r = 0; r < 4; ++r) {
        const float a = fabsf(acc[mi][ni][r] * iv[r]);
        l1r[r] += a;
        if (col == labr[r]) alr[r] += a;
      }
    }
#pragma unroll
    for (int r = 0; r < 4; ++r) {
#pragma unroll
      for (int off = 1; off < 16; off <<= 1) {
        l1r[r] += __shfl_xor(l1r[r], off);
        alr[r] += __shfl_xor(alr[r], off);
      }
    }
    if (m == 0) {
#pragma unroll
      for (int r = 0; r < 4; ++r) {
        l1part[w][mi * 16 + kg * 4 + r] = l1r[r];
        alpart[w][mi * 16 + kg * 4 + r] = alr[r];
      }
    }
  }
  __syncthreads();

  if (tid < ROWSB) {
    const float L = l1part[0][tid] + l1part[1][tid] + l1part[2][tid] + l1part[3][tid];
    const float A = alpart[0][tid] + alpart[1][tid] + alpart[2][tid] + alpart[3][tid];
    float c = lblLds[tid] ? (L - 2.f * A) / fmaxf(L, 1e-12f) : 0.f;
#pragma unroll
    for (int off = 1; off < 64; off <<= 1) c += __shfl_xor(c, off);
    if (tid == 0) atomicAdd(out, c);
  }
}

extern "C" void kernel_launch(void* const* d_in, const int* in_sizes, int n_in,
                              void* d_out, int out_size, void* d_ws, size_t ws_size,
                              hipStream_t stream) {
  const float* feats = (const float*)d_in[0];
  const float* centers = (const float*)d_in[1];
  const int* labels = (const int*)d_in[2];
  const int* labelled = (const int*)d_in[3];
  float* out = (float*)d_out;
  short* cnb2 = (short*)d_ws;  // [24][256][32] bf16 = 393216 B

  prep_centers_k<<<CPAD, 256, 0, stream>>>(centers, cnb2, out);
  cos_loss_k<<<NROWS / ROWSB, 256, 0, stream>>>(feats, cnb2, labels, labelled, out);
}